// Round 11
// baseline (174.416 us; speedup 1.0000x reference)
//
#include <hip/hip_runtime.h>
#include <cmath>

#define NC 6
#define CF 64
#define HH 88
#define WW 160
#define NPIX 14080     // 88*160
#define NVOX 200000
#define VPRE 64
#define VB 192         // voxels per block (thread = voxel for geometry; 3 waves)
#define NTH 512        // 8 waves
#define NWV 8

typedef unsigned int u32;

// ws layout
#define FEATT_BYTES  (6u * 64u * 14080u * 4u)            // 21,626,880
#define REC2_OFF     FEATT_BYTES
#define REC2_BYTES   (200000u * 32u)                     // worst case all voxels count-2
#define CNT_OFF      (REC2_OFF + REC2_BYTES)
#define WS_NEED      (CNT_OFF + 16u)

// ---------------- transpose [6][64][H*W] -> [6][H*W][64] (f32); also zeroes cnt ----------------
__global__ __launch_bounds__(256) void transpose_feats(const float* __restrict__ in,
                                                       float* __restrict__ out,
                                                       int* __restrict__ cnt) {
    __shared__ float tile[64 * 65];
    int blk = blockIdx.x;            // 6 * 220
    int c = blk / 220;
    int p0 = (blk - c * 220) * 64;
    int tid = threadIdx.x;
    int lane = tid & 63;
    int quad = tid >> 6;
    if (cnt && blk == 0 && tid == 0) cnt[0] = 0;
    for (int r = quad; r < 64; r += 4)
        tile[r * 65 + lane] = in[(c * 64 + r) * NPIX + p0 + lane];
    __syncthreads();
    for (int r = quad; r < 64; r += 4)
        out[((c * NPIX) + p0 + r) * 64 + lane] = tile[lane * 65 + r];
}

__device__ __forceinline__ float elu1(float x) { return x > 0.0f ? x : expm1f(x); }

// bilinear gather: voxel uniform across wave, lane = channel. Math identical to r3..r10.
__device__ __forceinline__ float gather_bilin(const float* __restrict__ fsrc, int useT,
                                              int lane, int cam, float x, float y) {
    float x0f = floorf(x), y0f = floorf(y);
    float wx1 = x - x0f, wx0 = 1.0f - wx1;
    float wy1 = y - y0f, wy0 = 1.0f - wy1;
    float x1f = x0f + 1.0f, y1f = y0f + 1.0f;
    float bx0 = (x0f >= 0.0f && x0f <= 159.0f) ? 1.0f : 0.0f;
    float bx1 = (x1f >= 0.0f && x1f <= 159.0f) ? 1.0f : 0.0f;
    float by0 = (y0f >= 0.0f && y0f <= 87.0f) ? 1.0f : 0.0f;
    float by1 = (y1f >= 0.0f && y1f <= 87.0f) ? 1.0f : 0.0f;
    int ix0 = (int)fminf(fmaxf(x0f, 0.0f), 159.0f);
    int ix1 = (int)fminf(fmaxf(x1f, 0.0f), 159.0f);
    int iy0 = (int)fminf(fmaxf(y0f, 0.0f), 87.0f);
    int iy1 = (int)fminf(fmaxf(y1f, 0.0f), 87.0f);
    int A = useT ? 64 : 1;
    int Boff = useT ? (cam * NPIX * 64 + lane) : ((cam * 64 + lane) * NPIX);
    float v00 = fsrc[(iy0 * WW + ix0) * A + Boff];
    float v01 = fsrc[(iy1 * WW + ix0) * A + Boff];
    float v10 = fsrc[(iy0 * WW + ix1) * A + Boff];
    float v11 = fsrc[(iy1 * WW + ix1) * A + Boff];
    float fv;                                        // reference corner order
    fv  = (wx0 * wy0 * bx0 * by0) * v00;
    fv += (wx0 * wy1 * bx0 * by1) * v01;
    fv += (wx1 * wy0 * bx1 * by0) * v10;
    fv += (wx1 * wy1 * bx1 * by1) * v11;
    return fv;
}

// 8-output FMA step over 4 channels, weights via wave-uniform scalar loads
#define FMA8_STEP(W0,W1,W2,W3,W4,W5,W6,W7,CG,F0,F1,F2,F3) \
    a0 += W0[CG]*F0; a0 += W0[CG+1]*F1; a0 += W0[CG+2]*F2; a0 += W0[CG+3]*F3; \
    a1 += W1[CG]*F0; a1 += W1[CG+1]*F1; a1 += W1[CG+2]*F2; a1 += W1[CG+3]*F3; \
    a2 += W2[CG]*F0; a2 += W2[CG+1]*F1; a2 += W2[CG+2]*F2; a2 += W2[CG+3]*F3; \
    a3 += W3[CG]*F0; a3 += W3[CG+1]*F1; a3 += W3[CG+2]*F2; a3 += W3[CG+3]*F3; \
    a4 += W4[CG]*F0; a4 += W4[CG+1]*F1; a4 += W4[CG+2]*F2; a4 += W4[CG+3]*F3; \
    a5 += W5[CG]*F0; a5 += W5[CG+1]*F1; a5 += W5[CG+2]*F2; a5 += W5[CG+3]*F3; \
    a6 += W6[CG]*F0; a6 += W6[CG+1]*F1; a6 += W6[CG+2]*F2; a6 += W6[CG+3]*F3; \
    a7 += W7[CG]*F0; a7 += W7[CG+1]*F1; a7 += W7[CG+2]*F2; a7 += W7[CG+3]*F3;

#define STORE8(COL) \
    outp[(size_t)(obase + 0) * NVOX + COL] = elu1(a0); \
    outp[(size_t)(obase + 1) * NVOX + COL] = elu1(a1); \
    outp[(size_t)(obase + 2) * NVOX + COL] = elu1(a2); \
    outp[(size_t)(obase + 3) * NVOX + COL] = elu1(a3); \
    outp[(size_t)(obase + 4) * NVOX + COL] = elu1(a4); \
    outp[(size_t)(obase + 5) * NVOX + COL] = elu1(a5); \
    outp[(size_t)(obase + 6) * NVOX + COL] = elu1(a6); \
    outp[(size_t)(obase + 7) * NVOX + COL] = elu1(a7);

#define WNO_PTRS \
    const float* w0n = wno + (obase + 0) * 65; \
    const float* w1n = wno + (obase + 1) * 65; \
    const float* w2n = wno + (obase + 2) * 65; \
    const float* w3n = wno + (obase + 3) * 65; \
    const float* w4n = wno + (obase + 4) * 65; \
    const float* w5n = wno + (obase + 5) * 65; \
    const float* w6n = wno + (obase + 6) * 65; \
    const float* w7n = wno + (obase + 7) * 65;

#define WO_PTRS \
    const float* w0o = wo + (obase + 0) * 130; \
    const float* w1o = wo + (obase + 1) * 130; \
    const float* w2o = wo + (obase + 2) * 130; \
    const float* w3o = wo + (obase + 3) * 130; \
    const float* w4o = wo + (obase + 4) * 130; \
    const float* w5o = wo + (obase + 5) * 130; \
    const float* w6o = wo + (obase + 6) * 130; \
    const float* w7o = wo + (obase + 7) * 130;

// ---------------- k1: zero + geometry + count-1 tiles; count-2 -> global list ----------------
__global__ __launch_bounds__(NTH) void vox_fused(
    const float* __restrict__ feats,
    const float* __restrict__ featT,
    const float* __restrict__ mask,
    const float* __restrict__ Kg,
    const float* __restrict__ ext,
    const float* __restrict__ wno,   // [64][65]
    const float* __restrict__ bno,   // [64]
    const float* __restrict__ wo,    // [64][130]
    const float* __restrict__ bo,    // [64]
    float* __restrict__ outp,        // [64][200000]
    float4* __restrict__ grec2,      // global count-2 records (2 per entry), or null
    int* __restrict__ gcnt,          // global count-2 counter, or null
    int useT, int defer2)
{
    __shared__ float s_ext[72];
    __shared__ float s_K[54];
    __shared__ float s_F[65 * 66];                 // [channel][entry], stride 66
    __shared__ __align__(16) float4 s_rec1[VB];    // {x,y,z,meta}
    __shared__ __align__(16) float4 s_rec2[2 * VB];
    __shared__ int s_vox[64];
    __shared__ int s_n1, s_n2, s_base2;

    int tid = threadIdx.x;
    int lane = tid & 63;
    int wv = tid >> 6;               // 0..7
    int base = blockIdx.x * VB;
    int vlim = min(VB, NVOX - base); // last block: 128

    if (tid == 0) { s_n1 = 0; s_n2 = 0; }
    if (tid >= 256 && tid < 328) {
        int i = tid - 256;
        s_ext[i] = ext[(i / 12) * 16 + (i % 12)];
    }
    if (tid >= 384 && tid < 438) {
        int i = tid - 384; int cam = i / 9; int e = i - cam * 9;
        s_K[i] = Kg[cam * 16 + (e / 3) * 4 + (e % 3)];
    }

    // ---- phase 0: zero this block's output window (coalesced float4) ----
    {
        int ng4 = vlim >> 2;                       // float4 groups per row (vlim % 4 == 0)
        for (int i = tid; i < 64 * (VB / 4); i += NTH) {
            int r = i / (VB / 4), cg = i - r * (VB / 4);
            if (cg < ng4)
                *(float4*)(outp + (size_t)r * NVOX + base + (cg << 2)) =
                    make_float4(0.f, 0.f, 0.f, 0.f);
        }
    }
    __syncthreads();

    // ---- phase 1: per-voxel geometry over 6 cams (identical FP sequence) ----
    if (tid < vlim) {
        #pragma clang fp contract(off)
        int n = base + tid;
        int xi = n % 100;
        int t = n / 100;
        int yi = t % 100;
        int zi = t / 100;
        float X = -50.0f + (float)xi;
        float Y = -50.0f + (float)yi;
        float Z = -15.0f + 1.5f * (float)zi;
        int cnt = 0, cam0 = 0, cam1 = 0;
        float ax = 0.f, ay = 0.f, az = 0.f, bx = 0.f, by = 0.f, bz = 0.f;
        #pragma unroll
        for (int cam = 0; cam < NC; ++cam) {
            const float* E = s_ext + cam * 12;
            const float* Kk = s_K + cam * 9;
            float vl0 = E[0]*X + E[1]*Y + E[2]*Z + E[3];
            float vl1 = E[4]*X + E[5]*Y + E[6]*Z + E[7];
            float vl2 = E[8]*X + E[9]*Y + E[10]*Z + E[11];
            float c0 = Kk[0]*vl0 + Kk[1]*vl1 + Kk[2]*vl2;
            float c1 = Kk[3]*vl0 + Kk[4]*vl1 + Kk[5]*vl2;
            float c2 = Kk[6]*vl0 + Kk[7]*vl1 + Kk[8]*vl2;
            float pz = c2 + 1e-8f;
            float px = c0 / pz;
            float py = c1 / pz;
            float gx = (px / 159.0f - 0.5f) * 2.0f;
            float gy = (py / 87.0f - 0.5f) * 2.0f;
            float x = ((gx + 1.0f) * 0.5f) * 159.0f;
            float y = ((gy + 1.0f) * 0.5f) * 87.0f;
            float xr = rintf(x), yr = rintf(y);
            bool nv = (xr >= 0.0f) && (xr <= 159.0f) && (yr >= 0.0f) && (yr <= 87.0f);
            float mval = 0.0f;
            if (nv) mval = mask[(cam * HH + (int)yr) * WW + (int)xr];
            bool ok = (mval > 0.5f) && (vl2 > 0.0f) &&
                      !((gx > 1.0f) || (gx < -1.0f) || (gy > 1.0f) || (gy < -1.0f));
            if (ok) {
                if (cnt == 0) { ax = x; ay = y; az = vl2; cam0 = cam; }
                else if (cnt == 1) { bx = x; by = y; bz = vl2; cam1 = cam; }
                ++cnt;
            }
        }
        if (cnt == 1) {
            int s = atomicAdd(&s_n1, 1);
            s_rec1[s] = make_float4(ax, ay, az, __int_as_float((n << 3) | cam0));
        } else if (cnt == 2) {
            int s = atomicAdd(&s_n2, 1);
            s_rec2[2 * s + 0] = make_float4(ax, ay, az, __int_as_float((n << 3) | cam0));
            s_rec2[2 * s + 1] = make_float4(bx, by, bz, __int_as_float((n << 3) | cam1));
        }
    }
    __syncthreads();   // also orders zero-phase stores before result stores

    int n1 = s_n1, n2 = s_n2;
    const float* fsrc = useT ? featT : feats;
    int wvu = __builtin_amdgcn_readfirstlane(wv);
    int obase = wvu * 8;
    WNO_PTRS

    if (defer2) {
        // ---- export count-2 records to global list (block-aggregated atomic) ----
        if (n2 > 0) {
            if (tid == 0) s_base2 = atomicAdd(gcnt, n2);
            __syncthreads();
            int b2 = s_base2;
            for (int i = tid; i < 2 * n2; i += NTH)
                grec2[2 * b2 + i] = s_rec2[i];
        }
    }

    // ---- count==1 tiles ----
    for (int t0 = 0; t0 < n1; t0 += 64) {
        int tl = min(64, n1 - t0);
        for (int e = wv; e < tl; e += NWV) {
            float4 r = s_rec1[t0 + e];               // wave-uniform LDS broadcast
            int meta = __float_as_int(r.w);
            int cam = meta & 7;
            float fv = gather_bilin(fsrc, useT, lane, cam, r.x, r.y);
            s_F[lane * 66 + e] = fv;
            if (lane == 0) { s_F[64 * 66 + e] = r.z / 100.0f; s_vox[e] = meta >> 3; }
        }
        __syncthreads();
        float a0 = bno[obase + 0], a1 = bno[obase + 1], a2 = bno[obase + 2], a3 = bno[obase + 3];
        float a4 = bno[obase + 4], a5 = bno[obase + 5], a6 = bno[obase + 6], a7 = bno[obase + 7];
        for (int cg = 0; cg < 64; cg += 4) {
            float f0 = s_F[(cg + 0) * 66 + lane];
            float f1 = s_F[(cg + 1) * 66 + lane];
            float f2 = s_F[(cg + 2) * 66 + lane];
            float f3 = s_F[(cg + 3) * 66 + lane];
            FMA8_STEP(w0n, w1n, w2n, w3n, w4n, w5n, w6n, w7n, cg, f0, f1, f2, f3)
        }
        float fd = s_F[64 * 66 + lane];
        a0 += w0n[64] * fd; a1 += w1n[64] * fd; a2 += w2n[64] * fd; a3 += w3n[64] * fd;
        a4 += w4n[64] * fd; a5 += w5n[64] * fd; a6 += w6n[64] * fd; a7 += w7n[64] * fd;
        if (lane < tl) {
            size_t col = (size_t)s_vox[lane];
            STORE8(col)
        }
        __syncthreads();
    }

    if (!defer2) {
        // ---- fallback: count==2 tiles in-block (r10 path) ----
        WO_PTRS
        for (int t0 = 0; t0 < n2; t0 += 64) {
            int tl = min(64, n2 - t0);
            for (int e = wv; e < tl; e += NWV) {     // pass A gather: cams {0,3,4}
                float4 r0 = s_rec2[2 * (t0 + e) + 0];
                float4 r1 = s_rec2[2 * (t0 + e) + 1];
                int m0 = __float_as_int(r0.w), m1 = __float_as_int(r1.w);
                int ca = m0 & 7, cb = m1 & 7;
                float fg = 0.0f, dd = 0.0f;
                if (!(ca == 1 || ca == 2 || ca == 5)) {
                    fg += gather_bilin(fsrc, useT, lane, ca, r0.x, r0.y);
                    dd += r0.z / 100.0f;
                }
                if (!(cb == 1 || cb == 2 || cb == 5)) {
                    fg += gather_bilin(fsrc, useT, lane, cb, r1.x, r1.y);
                    dd += r1.z / 100.0f;
                }
                s_F[lane * 66 + e] = fg;
                if (lane == 0) { s_F[64 * 66 + e] = dd; s_vox[e] = m0 >> 3; }
            }
            __syncthreads();
            float a0 = bo[obase + 0], a1 = bo[obase + 1], a2 = bo[obase + 2], a3 = bo[obase + 3];
            float a4 = bo[obase + 4], a5 = bo[obase + 5], a6 = bo[obase + 6], a7 = bo[obase + 7];
            for (int cg = 0; cg < 64; cg += 4) {
                float f0 = s_F[(cg + 0) * 66 + lane];
                float f1 = s_F[(cg + 1) * 66 + lane];
                float f2 = s_F[(cg + 2) * 66 + lane];
                float f3 = s_F[(cg + 3) * 66 + lane];
                FMA8_STEP(w0o, w1o, w2o, w3o, w4o, w5o, w6o, w7o, cg, f0, f1, f2, f3)
            }
            {
                float fd = s_F[64 * 66 + lane];
                a0 += w0o[64] * fd; a1 += w1o[64] * fd; a2 += w2o[64] * fd; a3 += w3o[64] * fd;
                a4 += w4o[64] * fd; a5 += w5o[64] * fd; a6 += w6o[64] * fd; a7 += w7o[64] * fd;
            }
            __syncthreads();
            for (int e = wv; e < tl; e += NWV) {     // pass B gather: cams {1,2,5}
                float4 r0 = s_rec2[2 * (t0 + e) + 0];
                float4 r1 = s_rec2[2 * (t0 + e) + 1];
                int m0 = __float_as_int(r0.w), m1 = __float_as_int(r1.w);
                int ca = m0 & 7, cb = m1 & 7;
                float fg = 0.0f, dd = 0.0f;
                if (ca == 1 || ca == 2 || ca == 5) {
                    fg += gather_bilin(fsrc, useT, lane, ca, r0.x, r0.y);
                    dd += r0.z / 100.0f;
                }
                if (cb == 1 || cb == 2 || cb == 5) {
                    fg += gather_bilin(fsrc, useT, lane, cb, r1.x, r1.y);
                    dd += r1.z / 100.0f;
                }
                s_F[lane * 66 + e] = fg;
                if (lane == 0) s_F[64 * 66 + e] = dd;
            }
            __syncthreads();
            for (int cg = 0; cg < 64; cg += 4) {
                float f0 = s_F[(cg + 0) * 66 + lane];
                float f1 = s_F[(cg + 1) * 66 + lane];
                float f2 = s_F[(cg + 2) * 66 + lane];
                float f3 = s_F[(cg + 3) * 66 + lane];
                int cgo = cg + 65;
                FMA8_STEP(w0o, w1o, w2o, w3o, w4o, w5o, w6o, w7o, cgo, f0, f1, f2, f3)
            }
            {
                float fd = s_F[64 * 66 + lane];
                a0 += w0o[129] * fd; a1 += w1o[129] * fd; a2 += w2o[129] * fd; a3 += w3o[129] * fd;
                a4 += w4o[129] * fd; a5 += w5o[129] * fd; a6 += w6o[129] * fd; a7 += w7o[129] * fd;
            }
            if (lane < tl) {
                size_t col = (size_t)s_vox[lane];
                STORE8(col)
            }
            __syncthreads();
        }
    }
}

// ---------------- k2: count-2 full tiles from global list ----------------
__global__ __launch_bounds__(NTH) void vox_ov(
    const float* __restrict__ feats,
    const float* __restrict__ featT,
    const float4* __restrict__ rec2,
    const int* __restrict__ gcnt,
    const float* __restrict__ wo,    // [64][130]
    const float* __restrict__ bo,    // [64]
    float* __restrict__ outp,        // [64][200000], zeroed by k1
    int useT)
{
    __shared__ float s_F[65 * 66];
    __shared__ int s_vox[64];

    int tid = threadIdx.x;
    int lane = tid & 63;
    int wv = tid >> 6;
    int c2 = gcnt[0];
    int nt = (c2 + 63) >> 6;

    const float* fsrc = useT ? featT : feats;
    int wvu = __builtin_amdgcn_readfirstlane(wv);
    int obase = wvu * 8;
    WO_PTRS

    for (int t = blockIdx.x; t < nt; t += gridDim.x) {
        int e0 = t << 6;
        int tl = min(64, c2 - e0);
        for (int e = wv; e < tl; e += NWV) {         // pass A gather: cams {0,3,4}
            float4 r0 = rec2[2 * (e0 + e) + 0];
            float4 r1 = rec2[2 * (e0 + e) + 1];
            int m0 = __float_as_int(r0.w), m1 = __float_as_int(r1.w);
            int ca = m0 & 7, cb = m1 & 7;
            float fg = 0.0f, dd = 0.0f;
            if (!(ca == 1 || ca == 2 || ca == 5)) {
                fg += gather_bilin(fsrc, useT, lane, ca, r0.x, r0.y);
                dd += r0.z / 100.0f;
            }
            if (!(cb == 1 || cb == 2 || cb == 5)) {
                fg += gather_bilin(fsrc, useT, lane, cb, r1.x, r1.y);
                dd += r1.z / 100.0f;
            }
            s_F[lane * 66 + e] = fg;
            if (lane == 0) { s_F[64 * 66 + e] = dd; s_vox[e] = m0 >> 3; }
        }
        __syncthreads();
        float a0 = bo[obase + 0], a1 = bo[obase + 1], a2 = bo[obase + 2], a3 = bo[obase + 3];
        float a4 = bo[obase + 4], a5 = bo[obase + 5], a6 = bo[obase + 6], a7 = bo[obase + 7];
        for (int cg = 0; cg < 64; cg += 4) {         // pass A compute: cols 0..64
            float f0 = s_F[(cg + 0) * 66 + lane];
            float f1 = s_F[(cg + 1) * 66 + lane];
            float f2 = s_F[(cg + 2) * 66 + lane];
            float f3 = s_F[(cg + 3) * 66 + lane];
            FMA8_STEP(w0o, w1o, w2o, w3o, w4o, w5o, w6o, w7o, cg, f0, f1, f2, f3)
        }
        {
            float fd = s_F[64 * 66 + lane];
            a0 += w0o[64] * fd; a1 += w1o[64] * fd; a2 += w2o[64] * fd; a3 += w3o[64] * fd;
            a4 += w4o[64] * fd; a5 += w5o[64] * fd; a6 += w6o[64] * fd; a7 += w7o[64] * fd;
        }
        __syncthreads();
        for (int e = wv; e < tl; e += NWV) {         // pass B gather: cams {1,2,5}
            float4 r0 = rec2[2 * (e0 + e) + 0];
            float4 r1 = rec2[2 * (e0 + e) + 1];
            int m0 = __float_as_int(r0.w), m1 = __float_as_int(r1.w);
            int ca = m0 & 7, cb = m1 & 7;
            float fg = 0.0f, dd = 0.0f;
            if (ca == 1 || ca == 2 || ca == 5) {
                fg += gather_bilin(fsrc, useT, lane, ca, r0.x, r0.y);
                dd += r0.z / 100.0f;
            }
            if (cb == 1 || cb == 2 || cb == 5) {
                fg += gather_bilin(fsrc, useT, lane, cb, r1.x, r1.y);
                dd += r1.z / 100.0f;
            }
            s_F[lane * 66 + e] = fg;
            if (lane == 0) s_F[64 * 66 + e] = dd;
        }
        __syncthreads();
        for (int cg = 0; cg < 64; cg += 4) {         // pass B compute: cols 65..129
            float f0 = s_F[(cg + 0) * 66 + lane];
            float f1 = s_F[(cg + 1) * 66 + lane];
            float f2 = s_F[(cg + 2) * 66 + lane];
            float f3 = s_F[(cg + 3) * 66 + lane];
            int cgo = cg + 65;
            FMA8_STEP(w0o, w1o, w2o, w3o, w4o, w5o, w6o, w7o, cgo, f0, f1, f2, f3)
        }
        {
            float fd = s_F[64 * 66 + lane];
            a0 += w0o[129] * fd; a1 += w1o[129] * fd; a2 += w2o[129] * fd; a3 += w3o[129] * fd;
            a4 += w4o[129] * fd; a5 += w5o[129] * fd; a6 += w6o[129] * fd; a7 += w7o[129] * fd;
        }
        if (lane < tl) {
            size_t col = (size_t)s_vox[lane];
            STORE8(col)
        }
        __syncthreads();
    }
}

extern "C" void kernel_launch(void* const* d_in, const int* in_sizes, int n_in,
                              void* d_out, int out_size, void* d_ws, size_t ws_size,
                              hipStream_t stream) {
    const float* feats = (const float*)d_in[0];
    const float* mask  = (const float*)d_in[1];
    const float* Kg    = (const float*)d_in[2];
    const float* ext   = (const float*)d_in[3];
    const float* wno   = (const float*)d_in[4];
    const float* bno   = (const float*)d_in[5];
    const float* wo    = (const float*)d_in[6];
    const float* bo    = (const float*)d_in[7];
    float* outp = (float*)d_out;
    char* wsb = (char*)d_ws;
    float* featT = (float*)wsb;

    int useT = (ws_size >= (size_t)FEATT_BYTES) ? 1 : 0;
    int defer2 = (ws_size >= (size_t)WS_NEED) ? 1 : 0;   // constant: graph-safe
    float4* grec2 = defer2 ? (float4*)(wsb + REC2_OFF) : nullptr;
    int* gcnt = defer2 ? (int*)(wsb + CNT_OFF) : nullptr;

    if (useT) {
        transpose_feats<<<NC * 220, 256, 0, stream>>>(feats, featT, gcnt);
    }
    int nblk = (NVOX + VB - 1) / VB;                 // 1042
    vox_fused<<<nblk, NTH, 0, stream>>>(feats, featT, mask, Kg, ext,
                                        wno, bno, wo, bo, outp,
                                        grec2, gcnt, useT, defer2);
    if (defer2) {
        vox_ov<<<256, NTH, 0, stream>>>(feats, featT, grec2, gcnt,
                                        wo, bo, outp, useT);
    }
}